// Round 3
// baseline (742.699 us; speedup 1.0000x reference)
//
#include <hip/hip_runtime.h>
#include <stdint.h>
#include <math.h>

#define NB 4096
#define NT 1024

// Output layout (float32, concatenated in return order):
//   yseq_full: [NB][NT][4]  at offset 0
//   yseq:      [NB][NT][2]  at offset NB*NT*4
//   xseq:      [NB][NT][3]  at offset NB*NT*6

#if __has_builtin(__builtin_amdgcn_exp2f)
#define EXP2F __builtin_amdgcn_exp2f
#else
#define EXP2F exp2f
#endif
#if __has_builtin(__builtin_amdgcn_rcpf)
#define RCPF __builtin_amdgcn_rcpf
#else
#define RCPF(x) (1.0f / (x))
#endif

// 2*log2(e): tanh(y) = 1 - 2/(1+exp2(y*TS)); scale folded into W1/b1.
#define TS 2.885390081777927f

// DPP move, masked-out lanes read 0 (bound_ctrl=1). Full-rate VALU cross-lane.
template <int CTRL>
__device__ __forceinline__ float dppmov(float x) {
  return __int_as_float(
      __builtin_amdgcn_update_dpp(0, __float_as_int(x), CTRL, 0xF, 0xF, true));
}

// rotate-allreduce within each 16-lane row (verified rounds 0/1): after
// ror 8,4,2,1 every lane of the row holds the row sum. Two values interleaved.
__device__ __forceinline__ void rowred2(float& a, float& b) {
  a += dppmov<0x128>(a); b += dppmov<0x128>(b);  // row_ror:8
  a += dppmov<0x124>(a); b += dppmov<0x124>(b);  // row_ror:4
  a += dppmov<0x122>(a); b += dppmov<0x122>(b);  // row_ror:2
  a += dppmov<0x121>(a); b += dppmov<0x121>(b);  // row_ror:1
}
__device__ __forceinline__ float rowred1(float a) {
  a += dppmov<0x128>(a);
  a += dppmov<0x124>(a);
  a += dppmov<0x122>(a);
  a += dppmov<0x121>(a);
  return a;
}

// ---------------------------------------------------------------------------
// FUSED kernel: sequential x-recurrence + per-step CcNN = eC(z_t).
// LAYOUT: 16 lanes per chain (4 chains per wave), 1024 waves -> one wave on
// every SIMD of the 1024 SIMDs (round-2's 8-lane layout left half the
// machine empty at 512 waves). Per lane per RK stage: 1 r1 unit + 1 r2 unit
// (2 tanh), reduced with the verified ror-tree (rowred2) -> both S1 and S2
// replicated on all 16 lanes, no bcast, no own/other asymmetry.
// eC is fused: the z-window (10 y-values + 5 u-values) lives in shift
// registers; each lane evaluates eC hidden units cl and cl+16 (30 fma +
// 2 tanh per step) -- all independent of the RK critical path, so it fills
// the latency stalls (round-2 counters: VALUBusy 42% at 925 cyc/step wall).
// This deletes phase2 (~190 us) entirely.
// ---------------------------------------------------------------------------
__global__ __launch_bounds__(64) void fused_kernel(
    const float* __restrict__ u, const float* __restrict__ xz0,
    const float* __restrict__ r1W1, const float* __restrict__ r1b1,
    const float* __restrict__ r1W2, const float* __restrict__ r1b2,
    const float* __restrict__ r2W1, const float* __restrict__ r2b1,
    const float* __restrict__ r2W2, const float* __restrict__ r2b2,
    const float* __restrict__ eCW1, const float* __restrict__ eCb1,
    const float* __restrict__ eCW2, const float* __restrict__ eCb2,
    float* __restrict__ out) {
  const int tid = threadIdx.x;  // block = 64 threads = 1 wave
  const int cl = tid & 15;      // lane within chain
  const int chain = (blockIdx.x << 2) + (tid >> 4);  // 4 chains per block

  // RK per-lane weights: lane cl owns r1 hidden unit cl and r2 hidden unit cl.
  const float wA1 = r1W1[cl] * TS;
  const float wC1 = r1b1[cl] * TS;
  const float wP1 = r1W2[cl];
  const float wP1n2 = -2.0f * wP1;
  const float wA2 = r2W1[cl] * TS;       // weight on s1
  const float wB2 = r2W1[16 + cl] * TS;  // weight on s2
  const float wC2 = r2b1[cl] * TS;
  const float wP2 = r2W2[cl];
  const float wP2n2 = -2.0f * wP2;
  const float c1 = r1b2[0];
  const float c2 = r2b2[0];
  // Folded constants (identical algebra to the verified round-2 kernel):
  //   k0 = (u/6 + 1/6 - c1) - 0.1 s0 - S1
  //   k1 = (-0.2 + 1.5 c1 - 3 c2) - 0.1 s1 + 1.5 S1 - 3 S2
  //   k2 = (c2 - 0.2)             - 0.1 s2 + S2
  const float C0b = 1.0f / 6.0f - c1;
  const float C1 = -0.2f + 1.5f * c1 - 3.0f * c2;
  const float C2 = c2 - 0.2f;

  // eC per-lane weights: lane cl owns hidden units cl and cl+16. TS folded.
  float eWa[15], eWb[15];
#pragma unroll
  for (int i = 0; i < 15; ++i) {
    eWa[i] = eCW1[i * 32 + cl] * TS;
    eWb[i] = eCW1[i * 32 + cl + 16] * TS;
  }
  const float ebA = eCb1[cl] * TS;
  const float ebB = eCb1[cl + 16] * TS;
  const float ew2a = eCW2[cl];
  const float ew2b = eCW2[cl + 16];
  const float ew2an2 = -2.0f * ew2a;
  const float ew2bn2 = -2.0f * ew2b;
  const float ew2sum = ew2a + ew2b;
  const float eb2v = eCb2[0];

  const float* xzr = xz0 + chain * 18;
  float x0 = xzr[0];
  float x1 = xzr[1];

  // z window in shift registers: zy[0..9] = y-history pairs, zu[0..4] = u's.
  float zy[10], zu[5];
#pragma unroll
  for (int i = 0; i < 10; ++i) zy[i] = xzr[3 + i];
#pragma unroll
  for (int i = 0; i < 5; ++i) zu[i] = xzr[13 + i];

  // eC(z): 30 fma + 2 tanh per lane, ror-tree over 16 lanes = 32-unit sum.
  auto eC = [&]() -> float {
    float ha = ebA, hb = ebB;
#pragma unroll
    for (int i = 0; i < 10; ++i) {
      ha = __builtin_fmaf(zy[i], eWa[i], ha);
      hb = __builtin_fmaf(zy[i], eWb[i], hb);
    }
#pragma unroll
    for (int i = 0; i < 5; ++i) {
      ha = __builtin_fmaf(zu[i], eWa[10 + i], ha);
      hb = __builtin_fmaf(zu[i], eWb[10 + i], hb);
    }
    const float ra = RCPF(EXP2F(ha) + 1.0f);
    const float rb = RCPF(EXP2F(hb) + 1.0f);
    float pl = __builtin_fmaf(ew2an2, ra, ew2sum);
    pl = __builtin_fmaf(ew2bn2, rb, pl);
    pl = rowred1(pl);
    return pl + eb2v;
  };

  float x2 = eC();  // Cc0 (same code as in-loop -> yf[0][3] == yf[0][2])

  // Branchless store plan: 9 outputs/step, 16 lanes. Lanes 9-15 duplicate
  // lanes 2-8 (identical value to identical address -- benign).
  const int clp = (cl < 9) ? cl : (cl - 7);
  size_t idx0;
  int stride;
  if (clp < 4) {  // yseq_full cols 0..3
    idx0 = (size_t)chain * NT * 4 + clp;
    stride = 4;
  } else if (clp < 6) {  // yseq cols 0..1
    idx0 = (size_t)NB * NT * 4 + (size_t)chain * NT * 2 + (clp - 4);
    stride = 2;
  } else {  // xseq cols 0..2
    idx0 = (size_t)NB * NT * 6 + (size_t)chain * NT * 3 + (clp - 6);
    stride = 3;
  }
  float* sp = out + idx0;
  const bool selx0 = (clp == 0) || (clp == 4) || (clp == 6);
  const bool selx1 = (clp == 1) || (clp == 5) || (clp == 7);
  const bool selCc = (clp == 3);

  float C0t;
  // One RK stage: 2 tanh per lane, ror-tree reduce, literal k coefficients
  // (same values as the verified per-lane aO/aT form).
  auto stage = [&](float s0, float s1, float s2, float& k0, float& k1,
                   float& k2) {
    const float u0 = __builtin_fmaf(-0.1f, s0, C0t);
    const float u1 = __builtin_fmaf(-0.1f, s1, C1);
    const float u2 = __builtin_fmaf(-0.1f, s2, C2);
    const float hA = __builtin_fmaf(s0, wA1, wC1);
    const float hB =
        __builtin_fmaf(s1, wA2, __builtin_fmaf(s2, wB2, wC2));
    const float rA = RCPF(EXP2F(hA) + 1.0f);
    const float rB = RCPF(EXP2F(hB) + 1.0f);
    float pA = __builtin_fmaf(wP1n2, rA, wP1);
    float pB = __builtin_fmaf(wP2n2, rB, wP2);
    rowred2(pA, pB);  // pA = S1, pB = S2 on all 16 lanes
    k0 = u0 - pA;
    k1 = __builtin_fmaf(-3.0f, pB, __builtin_fmaf(1.5f, pA, u1));
    k2 = u2 + pB;
  };

  const float* urow = u + (size_t)chain * NT;
  float4 ucur = *(const float4*)urow;
  for (int t4 = 0; t4 < NT; t4 += 4) {
    const int tn = (t4 + 4 < NT) ? (t4 + 4) : (NT - 4);
    const float4 unext = *(const float4*)(urow + tn);  // prefetch next group
    const float us4[4] = {ucur.x, ucur.y, ucur.z, ucur.w};
#pragma unroll
    for (int e = 0; e < 4; ++e) {
      const float uu = us4[e];
      // CcNN = eC(z_t): independent of this step's RK -> fills stalls.
      const float Cc = eC();
      // store the 9 outputs (branchless; one dword per lane)
      const float v = selx0 ? x0 : (selx1 ? x1 : (selCc ? Cc : x2));
      *sp = v;
      sp += stride;
      // shift z window: append current (x0, x1) and u_t
#pragma unroll
      for (int i = 0; i < 8; ++i) zy[i] = zy[i + 2];
      zy[8] = x0;
      zy[9] = x1;
#pragma unroll
      for (int i = 0; i < 4; ++i) zu[i] = zu[i + 1];
      zu[4] = uu;
      // RK4
      C0t = __builtin_fmaf(uu, 1.0f / 6.0f, C0b);
      float p0, p1, p2, q0, q1, q2;
      stage(x0, x1, x2, p0, p1, p2);  // k1
      float a0 = p0, a1 = p1, a2 = p2;
      stage(__builtin_fmaf(0.5f, p0, x0), __builtin_fmaf(0.5f, p1, x1),
            __builtin_fmaf(0.5f, p2, x2), q0, q1, q2);  // k2
      a0 = __builtin_fmaf(2.0f, q0, a0);
      a1 = __builtin_fmaf(2.0f, q1, a1);
      a2 = __builtin_fmaf(2.0f, q2, a2);
      stage(__builtin_fmaf(0.5f, q0, x0), __builtin_fmaf(0.5f, q1, x1),
            __builtin_fmaf(0.5f, q2, x2), p0, p1, p2);  // k3
      a0 = __builtin_fmaf(2.0f, p0, a0);
      a1 = __builtin_fmaf(2.0f, p1, a1);
      a2 = __builtin_fmaf(2.0f, p2, a2);
      stage(x0 + p0, x1 + p1, x2 + p2, q0, q1, q2);  // k4
      a0 += q0;
      a1 += q1;
      a2 += q2;
      x0 = __builtin_fmaf(1.0f / 6.0f, a0, x0);
      x1 = __builtin_fmaf(1.0f / 6.0f, a1, x1);
      x2 = __builtin_fmaf(1.0f / 6.0f, a2, x2);
    }
    ucur = unext;
  }
}

extern "C" void kernel_launch(void* const* d_in, const int* in_sizes, int n_in,
                              void* d_out, int out_size, void* d_ws,
                              size_t ws_size, hipStream_t stream) {
  const float* u = (const float*)d_in[0];
  const float* xz0 = (const float*)d_in[1];
  const float* r1W1 = (const float*)d_in[2];
  const float* r1b1 = (const float*)d_in[3];
  const float* r1W2 = (const float*)d_in[4];
  const float* r1b2 = (const float*)d_in[5];
  const float* r2W1 = (const float*)d_in[6];
  const float* r2b1 = (const float*)d_in[7];
  const float* r2W2 = (const float*)d_in[8];
  const float* r2b2 = (const float*)d_in[9];
  const float* eCW1 = (const float*)d_in[10];
  const float* eCb1 = (const float*)d_in[11];
  const float* eCW2 = (const float*)d_in[12];
  const float* eCb2 = (const float*)d_in[13];
  float* out = (float*)d_out;

  hipLaunchKernelGGL(fused_kernel, dim3(NB / 4), dim3(64), 0, stream, u, xz0,
                     r1W1, r1b1, r1W2, r1b2, r2W1, r2b1, r2W2, r2b2, eCW1,
                     eCb1, eCW2, eCb2, out);
}

// Round 4
// 685.655 us; speedup vs baseline: 1.0832x; 1.0832x over previous
//
#include <hip/hip_runtime.h>
#include <stdint.h>
#include <math.h>

#define NB 4096
#define NT 1024

// Output layout (float32, concatenated in return order):
//   yseq_full: [NB][NT][4]  at offset 0
//   yseq:      [NB][NT][2]  at offset NB*NT*4
//   xseq:      [NB][NT][3]  at offset NB*NT*6

#if __has_builtin(__builtin_amdgcn_exp2f)
#define EXP2F __builtin_amdgcn_exp2f
#else
#define EXP2F exp2f
#endif
#if __has_builtin(__builtin_amdgcn_rcpf)
#define RCPF __builtin_amdgcn_rcpf
#else
#define RCPF(x) (1.0f / (x))
#endif

// 2*log2(e): tanh(y) = 1 - 2/(1+exp2(y*TS)); scale folded into W1/b1.
#define TS 2.885390081777927f

// DPP move, masked-out lanes read 0 (bound_ctrl=1). Full-rate VALU cross-lane.
template <int CTRL>
__device__ __forceinline__ float dppmov(float x) {
  return __int_as_float(
      __builtin_amdgcn_update_dpp(0, __float_as_int(x), CTRL, 0xF, 0xF, true));
}

// rotate-allreduce within each 16-lane row (verified rounds 0-3): after
// ror 8,4,2,1 every lane of the row holds the row sum.
__device__ __forceinline__ void rowred2(float& a, float& b) {
  a += dppmov<0x128>(a); b += dppmov<0x128>(b);  // row_ror:8
  a += dppmov<0x124>(a); b += dppmov<0x124>(b);  // row_ror:4
  a += dppmov<0x122>(a); b += dppmov<0x122>(b);  // row_ror:2
  a += dppmov<0x121>(a); b += dppmov<0x121>(b);  // row_ror:1
}
__device__ __forceinline__ float rowred1(float a) {
  a += dppmov<0x128>(a);
  a += dppmov<0x124>(a);
  a += dppmov<0x122>(a);
  a += dppmov<0x121>(a);
  return a;
}

// ---------------------------------------------------------------------------
// Phase 1: sequential x-recurrence, 16 lanes/chain (4 chains/wave, 1024
// waves = every SIMD holds exactly one wave).
// Per lane per RK stage: ONE r1 unit + ONE r2 unit -> 4 trans ops (2 exp2 +
// 2 rcp) vs the 8-lane layout's 8. Counter post-mortem (r2 busy=389/42%,
// r3 busy=844) says trans issue ~8-16 cyc each dominates the in-order wave's
// issue stream: 32 trans/step was ~half the wall. This layout halves it.
// Stage-input algebra folded off the chain: hAx/hBx/u*x precomputed per step
// (x const within a step), so a stage is k_prev -> 1-2 fma -> trans chain ->
// reduce -> k. k-formulas keep round-2's exact operand order; all 16 lanes
// compute identical state (no divergence), stores branchless (lanes 8-15
// duplicate lanes 0-7: same value, same address - benign, verified r3).
// NO eC fusion: r3 proved in-order issue adds directly to the wall; eC stays
// in the throughput-mode phase2 kernel.
// ---------------------------------------------------------------------------
__global__ __launch_bounds__(64) void phase1_kernel(
    const float* __restrict__ u, const float* __restrict__ xz0,
    const float* __restrict__ r1W1, const float* __restrict__ r1b1,
    const float* __restrict__ r1W2, const float* __restrict__ r1b2,
    const float* __restrict__ r2W1, const float* __restrict__ r2b1,
    const float* __restrict__ r2W2, const float* __restrict__ r2b2,
    const float* __restrict__ eCW1, const float* __restrict__ eCb1,
    const float* __restrict__ eCW2, const float* __restrict__ eCb2,
    float* __restrict__ out) {
  const int tid = threadIdx.x;  // block = 64 threads = 1 wave
  const int cl = tid & 15;      // lane within chain
  const int chain = (blockIdx.x << 2) + (tid >> 4);  // 4 chains per block

  // Per-lane unit weights (lane cl owns r1 unit cl and r2 unit cl), TS folded.
  const float wA1 = r1W1[cl] * TS;
  const float wC1 = r1b1[cl] * TS;
  const float wP1 = r1W2[cl];
  const float wP1n2 = -2.0f * wP1;
  const float wA2 = r2W1[cl] * TS;       // weight on s1
  const float wB2 = r2W1[16 + cl] * TS;  // weight on s2
  const float wC2 = r2b1[cl] * TS;
  const float wP2 = r2W2[cl];
  const float wP2n2 = -2.0f * wP2;
  const float wA1h = 0.5f * wA1;  // half-step folded weights (stages 2,3)
  const float wA2h = 0.5f * wA2;
  const float wB2h = 0.5f * wB2;
  const float c1 = r1b2[0];
  const float c2 = r2b2[0];
  // Folded k constants (identical algebra/order to the verified r2 kernel):
  //   k0 = (u/6 + 1/6 - c1) - 0.1 s0 - S1
  //   k1 = (-0.2 + 1.5 c1 - 3 c2) - 0.1 s1 + 1.5 S1 - 3 S2
  //   k2 = (c2 - 0.2)             - 0.1 s2 + S2
  const float C0b = 1.0f / 6.0f - c1;
  const float C1 = -0.2f + 1.5f * c1 - 3.0f * c2;
  const float C2 = c2 - 0.2f;

  const float* xzr = xz0 + chain * 18;
  float x0 = xzr[0];
  float x1 = xzr[1];
  float x2;

  // x2 init = eC(z0): lane cl evaluates hidden units cl and cl+16 (one-time).
  {
    float ha = eCb1[cl] * TS, hb = eCb1[cl + 16] * TS;
#pragma unroll
    for (int i = 0; i < 15; ++i) {
      const float z = xzr[3 + i];
      ha = __builtin_fmaf(z, eCW1[i * 32 + cl] * TS, ha);
      hb = __builtin_fmaf(z, eCW1[i * 32 + cl + 16] * TS, hb);
    }
    const float w2a = eCW2[cl], w2b = eCW2[cl + 16];
    const float ra = RCPF(EXP2F(ha) + 1.0f);
    const float rb = RCPF(EXP2F(hb) + 1.0f);
    float pl = __builtin_fmaf(-2.0f * w2a, ra, w2a + w2b);
    pl = __builtin_fmaf(-2.0f * w2b, rb, pl);
    pl = rowred1(pl);
    x2 = pl + eCb2[0];
  }

  // Branchless store plan: 8 outputs/step, lanes 8-15 duplicate lanes 0-7.
  //   clp 0..2 -> yseq_full[chain][t][clp]   (stride 4)
  //   clp 3..4 -> yseq[chain][t][clp-3]      (stride 2)
  //   clp 5..7 -> xseq[chain][t][clp-5]      (stride 3)
  const int clp = (cl < 8) ? cl : (cl - 8);
  size_t idx0;
  int stride;
  if (clp < 3) {
    idx0 = (size_t)chain * NT * 4 + clp;
    stride = 4;
  } else if (clp < 5) {
    idx0 = (size_t)NB * NT * 4 + (size_t)chain * NT * 2 + (clp - 3);
    stride = 2;
  } else {
    idx0 = (size_t)NB * NT * 6 + (size_t)chain * NT * 3 + (clp - 5);
    stride = 3;
  }
  float* sp = out + idx0;
  const bool selx0 = (clp == 0) || (clp == 3) || (clp == 5);
  const bool selx1 = (clp == 1) || (clp == 4) || (clp == 6);

  // Two-net tanh + reduce: hA,hB -> S1,S2 replicated on all 16 lanes.
  auto nets = [&](float hA, float hB, float& S1, float& S2) {
    const float rA = RCPF(EXP2F(hA) + 1.0f);
    const float rB = RCPF(EXP2F(hB) + 1.0f);
    float pA = __builtin_fmaf(wP1n2, rA, wP1);
    float pB = __builtin_fmaf(wP2n2, rB, wP2);
    rowred2(pA, pB);
    S1 = pA;
    S2 = pB;
  };

  const float* urow = u + (size_t)chain * NT;
  float4 ucur = *(const float4*)urow;
  for (int t4 = 0; t4 < NT; t4 += 4) {
    const int tn = (t4 + 4 < NT) ? (t4 + 4) : (NT - 4);
    const float4 unext = *(const float4*)(urow + tn);  // prefetch next group
    const float us4[4] = {ucur.x, ucur.y, ucur.z, ucur.w};
#pragma unroll
    for (int e = 0; e < 4; ++e) {
      // store state at t (branchless; one dword per lane)
      const float v = selx0 ? x0 : (selx1 ? x1 : x2);
      *sp = v;
      sp += stride;
      // per-step folded terms (off the trans/reduce critical path)
      const float C0t = __builtin_fmaf(us4[e], 1.0f / 6.0f, C0b);
      const float u0x = __builtin_fmaf(-0.1f, x0, C0t);
      const float u1x = __builtin_fmaf(-0.1f, x1, C1);
      const float u2x = __builtin_fmaf(-0.1f, x2, C2);
      const float hAx = __builtin_fmaf(x0, wA1, wC1);
      const float hBx = __builtin_fmaf(x1, wA2, __builtin_fmaf(x2, wB2, wC2));
      float S1, S2;
      // ---- stage 1: inputs are x exactly -> h = hx, u = ux
      nets(hAx, hBx, S1, S2);
      const float k10 = u0x - S1;
      const float k11 =
          __builtin_fmaf(1.5f, S1, __builtin_fmaf(-3.0f, S2, u1x));
      const float k12 = u2x + S2;
      // ---- stage 2: s = x + 0.5 k1
      nets(__builtin_fmaf(wA1h, k10, hAx),
           __builtin_fmaf(wA2h, k11, __builtin_fmaf(wB2h, k12, hBx)), S1, S2);
      const float k20 = __builtin_fmaf(-0.05f, k10, u0x) - S1;
      const float k21 = __builtin_fmaf(
          1.5f, S1,
          __builtin_fmaf(-3.0f, S2, __builtin_fmaf(-0.05f, k11, u1x)));
      const float k22 = __builtin_fmaf(-0.05f, k12, u2x) + S2;
      // ---- stage 3: s = x + 0.5 k2
      nets(__builtin_fmaf(wA1h, k20, hAx),
           __builtin_fmaf(wA2h, k21, __builtin_fmaf(wB2h, k22, hBx)), S1, S2);
      const float k30 = __builtin_fmaf(-0.05f, k20, u0x) - S1;
      const float k31 = __builtin_fmaf(
          1.5f, S1,
          __builtin_fmaf(-3.0f, S2, __builtin_fmaf(-0.05f, k21, u1x)));
      const float k32 = __builtin_fmaf(-0.05f, k22, u2x) + S2;
      // ---- stage 4: s = x + k3
      nets(__builtin_fmaf(wA1, k30, hAx),
           __builtin_fmaf(wA2, k31, __builtin_fmaf(wB2, k32, hBx)), S1, S2);
      const float k40 = __builtin_fmaf(-0.1f, k30, u0x) - S1;
      const float k41 = __builtin_fmaf(
          1.5f, S1,
          __builtin_fmaf(-3.0f, S2, __builtin_fmaf(-0.1f, k31, u1x)));
      const float k42 = __builtin_fmaf(-0.1f, k32, u2x) + S2;
      // ---- update
      float a0 = k20 + k30;
      a0 = __builtin_fmaf(2.0f, a0, k10) + k40;
      x0 = __builtin_fmaf(1.0f / 6.0f, a0, x0);
      float a1 = k21 + k31;
      a1 = __builtin_fmaf(2.0f, a1, k11) + k41;
      x1 = __builtin_fmaf(1.0f / 6.0f, a1, x1);
      float a2 = k22 + k32;
      a2 = __builtin_fmaf(2.0f, a2, k12) + k42;
      x2 = __builtin_fmaf(1.0f / 6.0f, a2, x2);
    }
    ucur = unext;
  }
}

// ---------------------------------------------------------------------------
// Phase 2: CcNN = eC(z_t) for all (b,t), fully parallel. Verbatim the
// verified round-2 version (weights pre-scaled by TS in LDS, output weight
// folded into the rcp-fma).
// ---------------------------------------------------------------------------
__global__ __launch_bounds__(256) void phase2_kernel(
    const float* __restrict__ u, const float* __restrict__ xz0,
    const float* __restrict__ eCW1, const float* __restrict__ eCb1,
    const float* __restrict__ eCW2, const float* __restrict__ eCb2,
    float* __restrict__ out) {
  __shared__ float lw[32][16];
  __shared__ float lw2[32];
  const int tid = threadIdx.x;
  if (tid < 32) {
#pragma unroll
    for (int i = 0; i < 15; ++i) lw[tid][i] = eCW1[i * 32 + tid] * TS;
    lw[tid][15] = eCb1[tid] * TS;
    lw2[tid] = -2.0f * eCW2[tid];
  }
  __syncthreads();

  const int b = blockIdx.x;
  const int t0 = tid << 2;
  const float2* ysrow =
      (const float2*)(out + (size_t)NB * NT * 4) + (size_t)b * NT;
  const float* urow = u + (size_t)b * NT;
  const float* xzr = xz0 + b * 18;

  // window: times t' = t0-5 .. t0+2; t' < 0 comes from z0 (entry t'+5)
  float yw[16], uw[8];
#pragma unroll
  for (int idx = 0; idx < 8; ++idx) {
    const int tp = t0 - 5 + idx;
    float a, c, uu;
    if (tp >= 0) {
      const float2 h = ysrow[tp];
      a = h.x;
      c = h.y;
      uu = urow[tp];
    } else {
      a = xzr[3 + 2 * (tp + 5)];
      c = xzr[4 + 2 * (tp + 5)];
      uu = xzr[13 + (tp + 5)];
    }
    yw[2 * idx] = a;
    yw[2 * idx + 1] = c;
    uw[idx] = uu;
  }

  float acc[4] = {0.f, 0.f, 0.f, 0.f};
  for (int j = 0; j < 32; ++j) {
    const float4 wa = ((const float4*)lw[j])[0];
    const float4 wb = ((const float4*)lw[j])[1];
    const float4 wc = ((const float4*)lw[j])[2];
    const float4 wd = ((const float4*)lw[j])[3];  // .w = scaled bias
    const float w2n = lw2[j];
#pragma unroll
    for (int e = 0; e < 4; ++e) {
      float h = wd.w;
      h = __builtin_fmaf(yw[2 * e + 0], wa.x, h);
      h = __builtin_fmaf(yw[2 * e + 1], wa.y, h);
      h = __builtin_fmaf(yw[2 * e + 2], wa.z, h);
      h = __builtin_fmaf(yw[2 * e + 3], wa.w, h);
      h = __builtin_fmaf(yw[2 * e + 4], wb.x, h);
      h = __builtin_fmaf(yw[2 * e + 5], wb.y, h);
      h = __builtin_fmaf(yw[2 * e + 6], wb.z, h);
      h = __builtin_fmaf(yw[2 * e + 7], wb.w, h);
      h = __builtin_fmaf(yw[2 * e + 8], wc.x, h);
      h = __builtin_fmaf(yw[2 * e + 9], wc.y, h);
      h = __builtin_fmaf(uw[e + 0], wc.z, h);
      h = __builtin_fmaf(uw[e + 1], wc.w, h);
      h = __builtin_fmaf(uw[e + 2], wd.x, h);
      h = __builtin_fmaf(uw[e + 3], wd.y, h);
      h = __builtin_fmaf(uw[e + 4], wd.z, h);
      const float r = RCPF(EXP2F(h) + 1.0f);
      acc[e] = __builtin_fmaf(w2n, r, acc[e]);
    }
  }
  // C = b2 + sum(W2) (uniform addresses -> scalar loads, one-time)
  float sw = 0.0f;
#pragma unroll
  for (int j = 0; j < 32; ++j) sw += eCW2[j];
  const float C = eCb2[0] + sw;
  float* yfrow = out + (size_t)b * NT * 4;
#pragma unroll
  for (int e = 0; e < 4; ++e) {
    yfrow[(t0 + e) * 4 + 3] = acc[e] + C;
  }
}

extern "C" void kernel_launch(void* const* d_in, const int* in_sizes, int n_in,
                              void* d_out, int out_size, void* d_ws,
                              size_t ws_size, hipStream_t stream) {
  const float* u = (const float*)d_in[0];
  const float* xz0 = (const float*)d_in[1];
  const float* r1W1 = (const float*)d_in[2];
  const float* r1b1 = (const float*)d_in[3];
  const float* r1W2 = (const float*)d_in[4];
  const float* r1b2 = (const float*)d_in[5];
  const float* r2W1 = (const float*)d_in[6];
  const float* r2b1 = (const float*)d_in[7];
  const float* r2W2 = (const float*)d_in[8];
  const float* r2b2 = (const float*)d_in[9];
  const float* eCW1 = (const float*)d_in[10];
  const float* eCb1 = (const float*)d_in[11];
  const float* eCW2 = (const float*)d_in[12];
  const float* eCb2 = (const float*)d_in[13];
  float* out = (float*)d_out;

  hipLaunchKernelGGL(phase1_kernel, dim3(NB / 4), dim3(64), 0, stream, u, xz0,
                     r1W1, r1b1, r1W2, r1b2, r2W1, r2b1, r2W2, r2b2, eCW1,
                     eCb1, eCW2, eCb2, out);
  hipLaunchKernelGGL(phase2_kernel, dim3(NB), dim3(256), 0, stream, u, xz0,
                     eCW1, eCb1, eCW2, eCb2, out);
}

// Round 5
// 591.658 us; speedup vs baseline: 1.2553x; 1.1589x over previous
//
#include <hip/hip_runtime.h>
#include <stdint.h>
#include <math.h>

#define NB 4096
#define NT 1024

// Output layout (float32, concatenated in return order):
//   yseq_full: [NB][NT][4]  at offset 0
//   yseq:      [NB][NT][2]  at offset NB*NT*4
//   xseq:      [NB][NT][3]  at offset NB*NT*6

#if __has_builtin(__builtin_amdgcn_exp2f)
#define EXP2F __builtin_amdgcn_exp2f
#else
#define EXP2F exp2f
#endif
#if __has_builtin(__builtin_amdgcn_rcpf)
#define RCPF __builtin_amdgcn_rcpf
#else
#define RCPF(x) (1.0f / (x))
#endif

// 2*log2(e): tanh(y) = 1 - 2/(1+exp2(y*TS)); scale folded into W1/b1.
#define TS 2.885390081777927f

typedef float f32x2 __attribute__((ext_vector_type(2)));
__device__ __forceinline__ f32x2 sp2(float s) { return (f32x2){s, s}; }
#define FMA2(a, b, c) __builtin_elementwise_fma((a), (b), (c))

// DPP move, masked-out lanes read 0 (bound_ctrl=1). Full-rate VALU cross-lane.
template <int CTRL>
__device__ __forceinline__ float dppmov(float x) {
  return __int_as_float(
      __builtin_amdgcn_update_dpp(0, __float_as_int(x), CTRL, 0xF, 0xF, true));
}

// ---------------------------------------------------------------------------
// Phase 1: sequential x-recurrence. r2 skeleton (the measured-best): 8 lanes
// per chain (8 chains/wave, 512 waves), quad0 = 16 r1 units (4/lane),
// quad1 = 16 r2 units (4/lane); depth-3 reduce (quad_perm x2 + half_mirror).
// Model from rounds 0-4: trans ~16 issue-cyc each, DPP dep-link ~28 cyc;
// wall = max(issue, 4*(2 trans-lat + depth*DPP + fma links)). This round:
// (a) next-stage h computed DIRECTLY from (Sown,Soth) via per-lane linear
//     coefficients (1-2 fma on the path; k's move off-path),
// (b) unit-pairs packed as f32x2 -> v_pk_fma_f32 halves VALU issue.
// ---------------------------------------------------------------------------
__global__ __launch_bounds__(64) void phase1_kernel(
    const float* __restrict__ u, const float* __restrict__ xz0,
    const float* __restrict__ r1W1, const float* __restrict__ r1b1,
    const float* __restrict__ r1W2, const float* __restrict__ r1b2,
    const float* __restrict__ r2W1, const float* __restrict__ r2b1,
    const float* __restrict__ r2W2, const float* __restrict__ r2b2,
    const float* __restrict__ eCW1, const float* __restrict__ eCb1,
    const float* __restrict__ eCW2, const float* __restrict__ eCb2,
    float* __restrict__ out) {
  const int tid = threadIdx.x;  // block = 64 threads = 1 wave
  const int cl = tid & 7;       // lane within chain
  const int q = tid & 3;        // lane within quad
  const bool isQ1 = (tid & 4) != 0;  // quad1 = r2 lanes
  const int chain = (blockIdx.x << 3) + (tid >> 3);

  // per-lane weights: 4 hidden units of ONE net per lane (units q+4m), TS
  // folded. Packed as f32x2 pairs {m0,m1}, {m2,m3}.
  f32x2 wAv0, wAv1, wBv0, wBv1, wCv0, wCv1, wPn2v0, wPn2v1;
  float wPsum;
  {
    float wa[4], wb[4], wc[4], wp[4];
#pragma unroll
    for (int m = 0; m < 4; ++m) {
      const int un = q + 4 * m;
      if (!isQ1) {
        wa[m] = r1W1[un] * TS;
        wb[m] = 0.0f;  // r1 has a single input
        wc[m] = r1b1[un] * TS;
        wp[m] = r1W2[un];
      } else {
        wa[m] = r2W1[un] * TS;       // weight on s1
        wb[m] = r2W1[16 + un] * TS;  // weight on s2
        wc[m] = r2b1[un] * TS;
        wp[m] = r2W2[un];
      }
    }
    wAv0 = (f32x2){wa[0], wa[1]};
    wAv1 = (f32x2){wa[2], wa[3]};
    wBv0 = (f32x2){wb[0], wb[1]};
    wBv1 = (f32x2){wb[2], wb[3]};
    wCv0 = (f32x2){wc[0], wc[1]};
    wCv1 = (f32x2){wc[2], wc[3]};
    wPn2v0 = (f32x2){-2.0f * wp[0], -2.0f * wp[1]};
    wPn2v1 = (f32x2){-2.0f * wp[2], -2.0f * wp[3]};
    wPsum = wp[0] + wp[1] + wp[2] + wp[3];
  }
  const f32x2 wPh = {wPsum, 0.0f};
  const f32x2 zero2 = {0.0f, 0.0f};

  // pre-coefficients (half-step and full-step):  h_next = pre + etaOWN*Sown
  // + etaOTH*Soth, pre = hx + cwA*Ua + cwB*U2.
  //   quad0: etaOWN = -c*wA1 (Sown=S1), etaOTH = 0
  //   quad1: etaOWN = c*(wB2 - 3*wA2) (Sown=S2), etaOTH = 1.5*c*wA2 (Soth=S1)
  const f32x2 cwAh0 = 0.5f * wAv0, cwAh1 = 0.5f * wAv1;
  const f32x2 cwAf0 = wAv0, cwAf1 = wAv1;
  const f32x2 cwBh0 = 0.5f * wBv0, cwBh1 = 0.5f * wBv1;
  const f32x2 cwBf0 = wBv0, cwBf1 = wBv1;
  const f32x2 eOWNh0 =
      isQ1 ? (0.5f * wBv0 - 1.5f * wAv0) : (-0.5f * wAv0);
  const f32x2 eOWNh1 =
      isQ1 ? (0.5f * wBv1 - 1.5f * wAv1) : (-0.5f * wAv1);
  const f32x2 eOWNf0 = isQ1 ? (wBv0 - 3.0f * wAv0) : (-wAv0);
  const f32x2 eOWNf1 = isQ1 ? (wBv1 - 3.0f * wAv1) : (-wAv1);
  const f32x2 eOTHh0 = isQ1 ? (0.75f * wAv0) : zero2;
  const f32x2 eOTHh1 = isQ1 ? (0.75f * wAv1) : zero2;
  const f32x2 eOTHf0 = isQ1 ? (1.5f * wAv0) : zero2;
  const f32x2 eOTHf1 = isQ1 ? (1.5f * wAv1) : zero2;

  const float c1 = r1b2[0];
  const float c2 = r2b2[0];
  // Folded k constants (verified r2/r4 algebra):
  //   k0 = (u/6 + 1/6 - c1) - 0.1 s0 - S1
  //   k1 = (-0.2 + 1.5 c1 - 3 c2) - 0.1 s1 + 1.5 S1 - 3 S2
  //   k2 = (c2 - 0.2)             - 0.1 s2 + S2
  const float C0b = 1.0f / 6.0f - c1;
  const float C1 = -0.2f + 1.5f * c1 - 3.0f * c2;
  const float C2 = c2 - 0.2f;

  const float* xzr = xz0 + chain * 18;
  float x0 = xzr[0];
  float x1 = xzr[1];
  float x2;

  // x2 init = eC(z0): 4 units/lane over 8 lanes = 32 (verified r2 block).
  {
    float eh[4], ewn2[4];
    float ewsum = 0.0f;
#pragma unroll
    for (int m = 0; m < 4; ++m) {
      const int un = 4 * cl + m;
      eh[m] = eCb1[un];
      ewn2[m] = -2.0f * eCW2[un];
      ewsum += eCW2[un];
    }
#pragma unroll
    for (int i = 0; i < 15; ++i) {
      const float z = xzr[3 + i];
#pragma unroll
      for (int m = 0; m < 4; ++m)
        eh[m] = __builtin_fmaf(z, eCW1[i * 32 + 4 * cl + m], eh[m]);
    }
    float pl = ewsum;
#pragma unroll
    for (int m = 0; m < 4; ++m) {
      const float e = EXP2F(eh[m] * TS);
      const float r = RCPF(e + 1.0f);
      pl = __builtin_fmaf(ewn2[m], r, pl);
    }
    pl += dppmov<0xB1>(pl);   // quad_perm [1,0,3,2]
    pl += dppmov<0x4E>(pl);   // quad_perm [2,3,0,1]
    pl = pl + dppmov<0x141>(pl);  // row_half_mirror: add other quad
    x2 = pl + eCb2[0];
  }

  // Branchless store plan: 8 outputs/step, lane cl owns one (verified r2).
  //   cl 0..2 -> yseq_full[chain][t][cl]   (stride 4)
  //   cl 3..4 -> yseq[chain][t][cl-3]      (stride 2)
  //   cl 5..7 -> xseq[chain][t][cl-5]      (stride 3)
  size_t idx0;
  int stride;
  if (cl < 3) {
    idx0 = (size_t)chain * NT * 4 + cl;
    stride = 4;
  } else if (cl < 5) {
    idx0 = (size_t)NB * NT * 4 + (size_t)chain * NT * 2 + (cl - 3);
    stride = 2;
  } else {
    idx0 = (size_t)NB * NT * 6 + (size_t)chain * NT * 3 + (cl - 5);
    stride = 3;
  }
  float* sp = out + idx0;
  const bool selx0 = (cl == 0) || (cl == 3) || (cl == 5);
  const bool selx1 = (cl == 1) || (cl == 4) || (cl == 6);

  // tanh pair eval + depth-3 reduce: (h0,h1) -> Sown (own quad's 16-unit
  // sum) and Soth (the other quad's) on every lane.
  auto nets = [&](f32x2 h0, f32x2 h1, float& Sown, float& Soth) {
    f32x2 e0, e1, r01, r23;
    e0.x = EXP2F(h0.x);
    e0.y = EXP2F(h0.y);
    e1.x = EXP2F(h1.x);
    e1.y = EXP2F(h1.y);
    e0 = e0 + sp2(1.0f);
    e1 = e1 + sp2(1.0f);
    r01.x = RCPF(e0.x);
    r01.y = RCPF(e0.y);
    r23.x = RCPF(e1.x);
    r23.y = RCPF(e1.y);
    f32x2 acc = FMA2(wPn2v0, r01, wPh);
    acc = FMA2(wPn2v1, r23, acc);
    float pl = acc.x + acc.y;
    pl += dppmov<0xB1>(pl);
    pl += dppmov<0x4E>(pl);
    Sown = pl;
    Soth = dppmov<0x141>(pl);
  };

  const float* urow = u + (size_t)chain * NT;
  float4 ucur = *(const float4*)urow;
  for (int t4 = 0; t4 < NT; t4 += 4) {
    const int tn = (t4 + 4 < NT) ? (t4 + 4) : (NT - 4);
    const float4 unext = *(const float4*)(urow + tn);  // prefetch next group
    const float us4[4] = {ucur.x, ucur.y, ucur.z, ucur.w};
#pragma unroll
    for (int e = 0; e < 4; ++e) {
      // store state at t (branchless; one dword per lane)
      const float v = selx0 ? x0 : (selx1 ? x1 : x2);
      *sp = v;
      sp += stride;
      // per-step bases (off the critical path)
      const float C0t = __builtin_fmaf(us4[e], 1.0f / 6.0f, C0b);
      const float U0 = __builtin_fmaf(-0.1f, x0, C0t);
      const float U1 = __builtin_fmaf(-0.1f, x1, C1);
      const float U2 = __builtin_fmaf(-0.1f, x2, C2);
      const float sU = isQ1 ? x1 : x0;
      const float sV = isQ1 ? x2 : x0;  // quad0: wB=0 -> exact
      const f32x2 hx0 = FMA2(sp2(sU), wAv0, FMA2(sp2(sV), wBv0, wCv0));
      const f32x2 hx1 = FMA2(sp2(sU), wAv1, FMA2(sp2(sV), wBv1, wCv1));
      float So, St, S1, S2;
      // ---- stage 1: h = hx
      nets(hx0, hx1, So, St);
      S1 = isQ1 ? St : So;
      S2 = isQ1 ? So : St;
      const float k10 = U0 - S1;
      const float k11 =
          __builtin_fmaf(1.5f, S1, __builtin_fmaf(-3.0f, S2, U1));
      const float k12 = U2 + S2;
      // ---- stage 2: h = pre(U_1, c=1/2) + eta.h*(S_1)
      {
        const float Ua = isQ1 ? U1 : U0;
        const f32x2 p0 = FMA2(cwAh0, sp2(Ua), FMA2(cwBh0, sp2(U2), hx0));
        const f32x2 p1 = FMA2(cwAh1, sp2(Ua), FMA2(cwBh1, sp2(U2), hx1));
        const f32x2 h0 = FMA2(eOTHh0, sp2(St), FMA2(eOWNh0, sp2(So), p0));
        const f32x2 h1 = FMA2(eOTHh1, sp2(St), FMA2(eOWNh1, sp2(So), p1));
        nets(h0, h1, So, St);
      }
      const float U0_2 = __builtin_fmaf(-0.05f, k10, U0);
      const float U1_2 = __builtin_fmaf(-0.05f, k11, U1);
      const float U2_2 = __builtin_fmaf(-0.05f, k12, U2);
      S1 = isQ1 ? St : So;
      S2 = isQ1 ? So : St;
      const float k20 = U0_2 - S1;
      const float k21 =
          __builtin_fmaf(1.5f, S1, __builtin_fmaf(-3.0f, S2, U1_2));
      const float k22 = U2_2 + S2;
      // ---- stage 3: h = pre(U_2, c=1/2) + eta.h*(S_2)
      {
        const float Ua = isQ1 ? U1_2 : U0_2;
        const f32x2 p0 = FMA2(cwAh0, sp2(Ua), FMA2(cwBh0, sp2(U2_2), hx0));
        const f32x2 p1 = FMA2(cwAh1, sp2(Ua), FMA2(cwBh1, sp2(U2_2), hx1));
        const f32x2 h0 = FMA2(eOTHh0, sp2(St), FMA2(eOWNh0, sp2(So), p0));
        const f32x2 h1 = FMA2(eOTHh1, sp2(St), FMA2(eOWNh1, sp2(So), p1));
        nets(h0, h1, So, St);
      }
      const float U0_3 = __builtin_fmaf(-0.05f, k20, U0);
      const float U1_3 = __builtin_fmaf(-0.05f, k21, U1);
      const float U2_3 = __builtin_fmaf(-0.05f, k22, U2);
      S1 = isQ1 ? St : So;
      S2 = isQ1 ? So : St;
      const float k30 = U0_3 - S1;
      const float k31 =
          __builtin_fmaf(1.5f, S1, __builtin_fmaf(-3.0f, S2, U1_3));
      const float k32 = U2_3 + S2;
      // ---- stage 4: h = pre(U_3, c=1) + eta.f*(S_3)
      {
        const float Ua = isQ1 ? U1_3 : U0_3;
        const f32x2 p0 = FMA2(cwAf0, sp2(Ua), FMA2(cwBf0, sp2(U2_3), hx0));
        const f32x2 p1 = FMA2(cwAf1, sp2(Ua), FMA2(cwBf1, sp2(U2_3), hx1));
        const f32x2 h0 = FMA2(eOTHf0, sp2(St), FMA2(eOWNf0, sp2(So), p0));
        const f32x2 h1 = FMA2(eOTHf1, sp2(St), FMA2(eOWNf1, sp2(So), p1));
        nets(h0, h1, So, St);
      }
      const float U0_4 = __builtin_fmaf(-0.1f, k30, U0);
      const float U1_4 = __builtin_fmaf(-0.1f, k31, U1);
      const float U2_4 = __builtin_fmaf(-0.1f, k32, U2);
      S1 = isQ1 ? St : So;
      S2 = isQ1 ? So : St;
      const float k40 = U0_4 - S1;
      const float k41 =
          __builtin_fmaf(1.5f, S1, __builtin_fmaf(-3.0f, S2, U1_4));
      const float k42 = U2_4 + S2;
      // ---- update (verified r2/r4 association)
      float tA = k20 + k30;
      tA = __builtin_fmaf(2.0f, tA, k10) + k40;
      x0 = __builtin_fmaf(1.0f / 6.0f, tA, x0);
      float tB = k21 + k31;
      tB = __builtin_fmaf(2.0f, tB, k11) + k41;
      x1 = __builtin_fmaf(1.0f / 6.0f, tB, x1);
      float tC = k22 + k32;
      tC = __builtin_fmaf(2.0f, tC, k12) + k42;
      x2 = __builtin_fmaf(1.0f / 6.0f, tC, x2);
    }
    ucur = unext;
  }
}

// ---------------------------------------------------------------------------
// Phase 2: CcNN = eC(z_t) for all (b,t), fully parallel. Verbatim the
// verified round-2/4 version.
// ---------------------------------------------------------------------------
__global__ __launch_bounds__(256) void phase2_kernel(
    const float* __restrict__ u, const float* __restrict__ xz0,
    const float* __restrict__ eCW1, const float* __restrict__ eCb1,
    const float* __restrict__ eCW2, const float* __restrict__ eCb2,
    float* __restrict__ out) {
  __shared__ float lw[32][16];
  __shared__ float lw2[32];
  const int tid = threadIdx.x;
  if (tid < 32) {
#pragma unroll
    for (int i = 0; i < 15; ++i) lw[tid][i] = eCW1[i * 32 + tid] * TS;
    lw[tid][15] = eCb1[tid] * TS;
    lw2[tid] = -2.0f * eCW2[tid];
  }
  __syncthreads();

  const int b = blockIdx.x;
  const int t0 = tid << 2;
  const float2* ysrow =
      (const float2*)(out + (size_t)NB * NT * 4) + (size_t)b * NT;
  const float* urow = u + (size_t)b * NT;
  const float* xzr = xz0 + b * 18;

  // window: times t' = t0-5 .. t0+2; t' < 0 comes from z0 (entry t'+5)
  float yw[16], uw[8];
#pragma unroll
  for (int idx = 0; idx < 8; ++idx) {
    const int tp = t0 - 5 + idx;
    float a, c, uu;
    if (tp >= 0) {
      const float2 h = ysrow[tp];
      a = h.x;
      c = h.y;
      uu = urow[tp];
    } else {
      a = xzr[3 + 2 * (tp + 5)];
      c = xzr[4 + 2 * (tp + 5)];
      uu = xzr[13 + (tp + 5)];
    }
    yw[2 * idx] = a;
    yw[2 * idx + 1] = c;
    uw[idx] = uu;
  }

  float acc[4] = {0.f, 0.f, 0.f, 0.f};
  for (int j = 0; j < 32; ++j) {
    const float4 wa = ((const float4*)lw[j])[0];
    const float4 wb = ((const float4*)lw[j])[1];
    const float4 wc = ((const float4*)lw[j])[2];
    const float4 wd = ((const float4*)lw[j])[3];  // .w = scaled bias
    const float w2n = lw2[j];
#pragma unroll
    for (int e = 0; e < 4; ++e) {
      float h = wd.w;
      h = __builtin_fmaf(yw[2 * e + 0], wa.x, h);
      h = __builtin_fmaf(yw[2 * e + 1], wa.y, h);
      h = __builtin_fmaf(yw[2 * e + 2], wa.z, h);
      h = __builtin_fmaf(yw[2 * e + 3], wa.w, h);
      h = __builtin_fmaf(yw[2 * e + 4], wb.x, h);
      h = __builtin_fmaf(yw[2 * e + 5], wb.y, h);
      h = __builtin_fmaf(yw[2 * e + 6], wb.z, h);
      h = __builtin_fmaf(yw[2 * e + 7], wb.w, h);
      h = __builtin_fmaf(yw[2 * e + 8], wc.x, h);
      h = __builtin_fmaf(yw[2 * e + 9], wc.y, h);
      h = __builtin_fmaf(uw[e + 0], wc.z, h);
      h = __builtin_fmaf(uw[e + 1], wc.w, h);
      h = __builtin_fmaf(uw[e + 2], wd.x, h);
      h = __builtin_fmaf(uw[e + 3], wd.y, h);
      h = __builtin_fmaf(uw[e + 4], wd.z, h);
      const float r = RCPF(EXP2F(h) + 1.0f);
      acc[e] = __builtin_fmaf(w2n, r, acc[e]);
    }
  }
  // C = b2 + sum(W2) (uniform addresses -> scalar loads, one-time)
  float sw = 0.0f;
#pragma unroll
  for (int j = 0; j < 32; ++j) sw += eCW2[j];
  const float C = eCb2[0] + sw;
  float* yfrow = out + (size_t)b * NT * 4;
#pragma unroll
  for (int e = 0; e < 4; ++e) {
    yfrow[(t0 + e) * 4 + 3] = acc[e] + C;
  }
}

extern "C" void kernel_launch(void* const* d_in, const int* in_sizes, int n_in,
                              void* d_out, int out_size, void* d_ws,
                              size_t ws_size, hipStream_t stream) {
  const float* u = (const float*)d_in[0];
  const float* xz0 = (const float*)d_in[1];
  const float* r1W1 = (const float*)d_in[2];
  const float* r1b1 = (const float*)d_in[3];
  const float* r1W2 = (const float*)d_in[4];
  const float* r1b2 = (const float*)d_in[5];
  const float* r2W1 = (const float*)d_in[6];
  const float* r2b1 = (const float*)d_in[7];
  const float* r2W2 = (const float*)d_in[8];
  const float* r2b2 = (const float*)d_in[9];
  const float* eCW1 = (const float*)d_in[10];
  const float* eCb1 = (const float*)d_in[11];
  const float* eCW2 = (const float*)d_in[12];
  const float* eCb2 = (const float*)d_in[13];
  float* out = (float*)d_out;

  hipLaunchKernelGGL(phase1_kernel, dim3(NB / 8), dim3(64), 0, stream, u, xz0,
                     r1W1, r1b1, r1W2, r1b2, r2W1, r2b1, r2W2, r2b2, eCW1,
                     eCb1, eCW2, eCb2, out);
  hipLaunchKernelGGL(phase2_kernel, dim3(NB), dim3(256), 0, stream, u, xz0,
                     eCW1, eCb1, eCW2, eCb2, out);
}

// Round 7
// 581.766 us; speedup vs baseline: 1.2766x; 1.0170x over previous
//
#include <hip/hip_runtime.h>
#include <stdint.h>
#include <math.h>

#define NB 4096
#define NT 1024

// Output layout (float32, concatenated in return order):
//   yseq_full: [NB][NT][4]  at offset 0
//   yseq:      [NB][NT][2]  at offset NB*NT*4
//   xseq:      [NB][NT][3]  at offset NB*NT*6

#if __has_builtin(__builtin_amdgcn_exp2f)
#define EXP2F __builtin_amdgcn_exp2f
#else
#define EXP2F exp2f
#endif
#if __has_builtin(__builtin_amdgcn_rcpf)
#define RCPF __builtin_amdgcn_rcpf
#else
#define RCPF(x) (1.0f / (x))
#endif

// 2*log2(e): tanh(y) = 1 - 2/(1+exp2(y*TS)); scale folded into W1/b1.
#define TS 2.885390081777927f

typedef float f32x2 __attribute__((ext_vector_type(2)));
__device__ __forceinline__ f32x2 sp2(float s) { return (f32x2){s, s}; }
#define FMA2(a, b, c) __builtin_elementwise_fma((a), (b), (c))

// DPP move, masked-out lanes read 0 (bound_ctrl=1). Full-rate VALU cross-lane.
template <int CTRL>
__device__ __forceinline__ float dppmov(float x) {
  return __int_as_float(
      __builtin_amdgcn_update_dpp(0, __float_as_int(x), CTRL, 0xF, 0xF, true));
}

// ---------------------------------------------------------------------------
// Phase 1: sequential x-recurrence. r2 skeleton: 8 lanes/chain (8 chains per
// wave, 512 waves), quad0 = 16 r1 units (4/lane), quad1 = 16 r2 units
// (4/lane); depth-3 reduce (quad_perm x2 + half_mirror).
// ROUND 6/7: TRUE software pipelining. r5 failed to shorten the path because
// pre3/pre4/step-boundary chained through k <- S of the IMMEDIATELY
// preceding stage. Fix: express each stage's pre from the stage-BEFORE's S:
//   U_2 = U - 0.05 k1       (from S1, during stage-2 flight)
//   U_3 = U - 0.05 k2       (from S2, during stage-3 flight)
//   U_4 = U - 0.1  k3, P = x + (k1+2k2+2k3+U_4)/6, preH = W.P + b,
//   pU = -0.1 P + C_next    (from S3, during stage-4 flight)
// Then every close is 2 fma after (So,St):
//   h_next = pre + etaOWN*So + etaOTH*St ; x_new = P + (1/6) M.S4;
//   h1' = preH + (etaF/6).S4 ; U' = pU - (0.1/6) M.S4.
// Critical path/stage: 2fma + exp2 + add + rcp + 2fma + add + 3dpp ~ 11
// links (was ~18). Wall model (r0-r5 fits): wall ~ links x ~13cyc, floor at
// issue ~730 cyc/step.
// ---------------------------------------------------------------------------
__global__ __launch_bounds__(64) void phase1_kernel(
    const float* __restrict__ u, const float* __restrict__ xz0,
    const float* __restrict__ r1W1, const float* __restrict__ r1b1,
    const float* __restrict__ r1W2, const float* __restrict__ r1b2,
    const float* __restrict__ r2W1, const float* __restrict__ r2b1,
    const float* __restrict__ r2W2, const float* __restrict__ r2b2,
    const float* __restrict__ eCW1, const float* __restrict__ eCb1,
    const float* __restrict__ eCW2, const float* __restrict__ eCb2,
    float* __restrict__ out) {
  const int tid = threadIdx.x;  // block = 64 threads = 1 wave
  const int cl = tid & 7;       // lane within chain
  const int q = tid & 3;        // lane within quad
  const bool isQ1 = (tid & 4) != 0;  // quad1 = r2 lanes
  const int chain = (blockIdx.x << 3) + (tid >> 3);

  // per-lane weights: 4 hidden units of ONE net per lane (units q+4m), TS
  // folded. Packed as f32x2 pairs {m0,m1}, {m2,m3}.
  f32x2 wAv0, wAv1, wBv0, wBv1, wCv0, wCv1, wPn2v0, wPn2v1;
  float wPsum;
  {
    float wa[4], wb[4], wc[4], wp[4];
#pragma unroll
    for (int m = 0; m < 4; ++m) {
      const int un = q + 4 * m;
      if (!isQ1) {
        wa[m] = r1W1[un] * TS;
        wb[m] = 0.0f;  // r1 has a single input
        wc[m] = r1b1[un] * TS;
        wp[m] = r1W2[un];
      } else {
        wa[m] = r2W1[un] * TS;       // weight on s1
        wb[m] = r2W1[16 + un] * TS;  // weight on s2
        wc[m] = r2b1[un] * TS;
        wp[m] = r2W2[un];
      }
    }
    wAv0 = (f32x2){wa[0], wa[1]};
    wAv1 = (f32x2){wa[2], wa[3]};
    wBv0 = (f32x2){wb[0], wb[1]};
    wBv1 = (f32x2){wb[2], wb[3]};
    wCv0 = (f32x2){wc[0], wc[1]};
    wCv1 = (f32x2){wc[2], wc[3]};
    wPn2v0 = (f32x2){-2.0f * wp[0], -2.0f * wp[1]};
    wPn2v1 = (f32x2){-2.0f * wp[2], -2.0f * wp[3]};
    wPsum = wp[0] + wp[1] + wp[2] + wp[3];
  }
  const f32x2 wPh = {wPsum, 0.0f};
  const f32x2 zero2 = {0.0f, 0.0f};

  // h-close coefficients: h = pre + etaOWN*So + etaOTH*St.
  //   quad0 (So=S1): etaF = {-wA, 0}
  //   quad1 (So=S2, St=S1): etaF = {wB-3wA, 1.5wA}
  // half-step (stages 2,3) = 0.5*etaF; step-boundary = etaF/6.
  const f32x2 cwAh0 = 0.5f * wAv0, cwAh1 = 0.5f * wAv1;
  const f32x2 cwBh0 = 0.5f * wBv0, cwBh1 = 0.5f * wBv1;
  const f32x2 eOWNf0 = isQ1 ? (wBv0 - 3.0f * wAv0) : (-wAv0);
  const f32x2 eOWNf1 = isQ1 ? (wBv1 - 3.0f * wAv1) : (-wAv1);
  const f32x2 eOTHf0 = isQ1 ? (1.5f * wAv0) : zero2;
  const f32x2 eOTHf1 = isQ1 ? (1.5f * wAv1) : zero2;
  const f32x2 eOWNh0 = 0.5f * eOWNf0, eOWNh1 = 0.5f * eOWNf1;
  const f32x2 eOTHh0 = 0.5f * eOTHf0, eOTHh1 = 0.5f * eOTHf1;
  const f32x2 eOWN60 = (1.0f / 6.0f) * eOWNf0, eOWN61 = (1.0f / 6.0f) * eOWNf1;
  const f32x2 eOTH60 = (1.0f / 6.0f) * eOTHf0, eOTH61 = (1.0f / 6.0f) * eOTHf1;

  const float c1 = r1b2[0];
  const float c2 = r2b2[0];
  // Folded k constants (verified r2/r4/r5 algebra):
  //   k0 = (u/6 + 1/6 - c1) - 0.1 s0 - S1
  //   k1 = (-0.2 + 1.5 c1 - 3 c2) - 0.1 s1 + 1.5 S1 - 3 S2
  //   k2 = (c2 - 0.2)             - 0.1 s2 + S2
  const float C0b = 1.0f / 6.0f - c1;
  const float C1 = -0.2f + 1.5f * c1 - 3.0f * c2;
  const float C2 = c2 - 0.2f;

  const float* xzr = xz0 + chain * 18;
  float x0 = xzr[0];
  float x1 = xzr[1];
  float x2;

  // x2 init = eC(z0): 4 units/lane over 8 lanes = 32 (verified r2 block).
  {
    float eh[4], ewn2[4];
    float ewsum = 0.0f;
#pragma unroll
    for (int m = 0; m < 4; ++m) {
      const int un = 4 * cl + m;
      eh[m] = eCb1[un];
      ewn2[m] = -2.0f * eCW2[un];
      ewsum += eCW2[un];
    }
#pragma unroll
    for (int i = 0; i < 15; ++i) {
      const float z = xzr[3 + i];
#pragma unroll
      for (int m = 0; m < 4; ++m)
        eh[m] = __builtin_fmaf(z, eCW1[i * 32 + 4 * cl + m], eh[m]);
    }
    float pl = ewsum;
#pragma unroll
    for (int m = 0; m < 4; ++m) {
      const float e = EXP2F(eh[m] * TS);
      const float r = RCPF(e + 1.0f);
      pl = __builtin_fmaf(ewn2[m], r, pl);
    }
    pl += dppmov<0xB1>(pl);       // quad_perm [1,0,3,2]
    pl += dppmov<0x4E>(pl);       // quad_perm [2,3,0,1]
    pl = pl + dppmov<0x141>(pl);  // row_half_mirror: add other quad
    x2 = pl + eCb2[0];
  }

  // Branchless store plan: 8 outputs/step, lane cl owns one (verified r2).
  size_t idx0;
  int stride;
  if (cl < 3) {
    idx0 = (size_t)chain * NT * 4 + cl;
    stride = 4;
  } else if (cl < 5) {
    idx0 = (size_t)NB * NT * 4 + (size_t)chain * NT * 2 + (cl - 3);
    stride = 2;
  } else {
    idx0 = (size_t)NB * NT * 6 + (size_t)chain * NT * 3 + (cl - 5);
    stride = 3;
  }
  float* sp = out + idx0;
  const bool selx0 = (cl == 0) || (cl == 3) || (cl == 5);
  const bool selx1 = (cl == 1) || (cl == 4) || (cl == 6);

  // tanh pair eval + depth-3 reduce.
  auto nets = [&](f32x2 h0, f32x2 h1, float& Sown, float& Soth) {
    f32x2 e0, e1, r01, r23;
    e0.x = EXP2F(h0.x);
    e0.y = EXP2F(h0.y);
    e1.x = EXP2F(h1.x);
    e1.y = EXP2F(h1.y);
    e0 = e0 + sp2(1.0f);
    e1 = e1 + sp2(1.0f);
    r01.x = RCPF(e0.x);
    r01.y = RCPF(e0.y);
    r23.x = RCPF(e1.x);
    r23.y = RCPF(e1.y);
    f32x2 acc = FMA2(wPn2v0, r01, wPh);
    acc = FMA2(wPn2v1, r23, acc);
    float pl = acc.x + acc.y;
    pl += dppmov<0xB1>(pl);
    pl += dppmov<0x4E>(pl);
    Sown = pl;
    Soth = dppmov<0x141>(pl);
  };

  const float* urow = u + (size_t)chain * NT;
  float4 ucur = *(const float4*)urow;

  // ---- pipeline prologue: U(t=0), h1 = W.x + b, pre2 = h1 + 0.5*Wrow.U
  float U0 = __builtin_fmaf(-0.1f, x0,
                            __builtin_fmaf(ucur.x, 1.0f / 6.0f, C0b));
  float U1 = __builtin_fmaf(-0.1f, x1, C1);
  float U2 = __builtin_fmaf(-0.1f, x2, C2);
  f32x2 h1v0, h1v1, pre2v0, pre2v1;
  {
    const float sU = isQ1 ? x1 : x0;
    const float sV = isQ1 ? x2 : x0;
    h1v0 = FMA2(wAv0, sp2(sU), FMA2(wBv0, sp2(sV), wCv0));
    h1v1 = FMA2(wAv1, sp2(sU), FMA2(wBv1, sp2(sV), wCv1));
    const float Ua = isQ1 ? U1 : U0;
    pre2v0 = FMA2(cwAh0, sp2(Ua), FMA2(cwBh0, sp2(U2), h1v0));
    pre2v1 = FMA2(cwAh1, sp2(Ua), FMA2(cwBh1, sp2(U2), h1v1));
  }

  for (int t4 = 0; t4 < NT; t4 += 4) {
    const int tn = (t4 + 4 < NT) ? (t4 + 4) : (NT - 4);
    const float4 unext = *(const float4*)(urow + tn);  // prefetch next group
    const float us4[4] = {ucur.x, ucur.y, ucur.z, ucur.w};
#pragma unroll
    for (int e = 0; e < 4; ++e) {
      // store state at t (branchless; one dword per lane)
      const float v = selx0 ? x0 : (selx1 ? x1 : x2);
      *sp = v;
      sp += stride;
      // u_{t+1} (garbage at the very last step; feeds nothing stored)
      const float unx = (e < 3) ? us4[e + 1] : unext.x;
      float So, St, S1, S2;
      // ================= stage 1 =================
      nets(h1v0, h1v1, So, St);
      // close h2 (2 fma from S1-arrival)
      const f32x2 h2v0 = FMA2(eOTHh0, sp2(St), FMA2(eOWNh0, sp2(So), pre2v0));
      const f32x2 h2v1 = FMA2(eOTHh1, sp2(St), FMA2(eOWNh1, sp2(So), pre2v1));
      // off-path (during stage-2 flight): k1, U_2, pre3
      S1 = isQ1 ? St : So;
      S2 = isQ1 ? So : St;
      const float k10 = U0 - S1;
      const float k11 =
          __builtin_fmaf(1.5f, S1, __builtin_fmaf(-3.0f, S2, U1));
      const float k12 = U2 + S2;
      const float U0_2 = __builtin_fmaf(-0.05f, k10, U0);
      const float U1_2 = __builtin_fmaf(-0.05f, k11, U1);
      const float U2_2 = __builtin_fmaf(-0.05f, k12, U2);
      const float Ua2 = isQ1 ? U1_2 : U0_2;
      const f32x2 pre3v0 = FMA2(cwAh0, sp2(Ua2), FMA2(cwBh0, sp2(U2_2), h1v0));
      const f32x2 pre3v1 = FMA2(cwAh1, sp2(Ua2), FMA2(cwBh1, sp2(U2_2), h1v1));
      // ================= stage 2 =================
      nets(h2v0, h2v1, So, St);
      const f32x2 h3v0 = FMA2(eOTHh0, sp2(St), FMA2(eOWNh0, sp2(So), pre3v0));
      const f32x2 h3v1 = FMA2(eOTHh1, sp2(St), FMA2(eOWNh1, sp2(So), pre3v1));
      // off-path: k2, U_3, pre4 (full-step coefficients)
      S1 = isQ1 ? St : So;
      S2 = isQ1 ? So : St;
      const float k20 = U0_2 - S1;
      const float k21 =
          __builtin_fmaf(1.5f, S1, __builtin_fmaf(-3.0f, S2, U1_2));
      const float k22 = U2_2 + S2;
      const float U0_3 = __builtin_fmaf(-0.05f, k20, U0);
      const float U1_3 = __builtin_fmaf(-0.05f, k21, U1);
      const float U2_3 = __builtin_fmaf(-0.05f, k22, U2);
      const float Ua3 = isQ1 ? U1_3 : U0_3;
      const f32x2 pre4v0 = FMA2(wAv0, sp2(Ua3), FMA2(wBv0, sp2(U2_3), h1v0));
      const f32x2 pre4v1 = FMA2(wAv1, sp2(Ua3), FMA2(wBv1, sp2(U2_3), h1v1));
      // ================= stage 3 =================
      nets(h3v0, h3v1, So, St);
      const f32x2 h4v0 = FMA2(eOTHf0, sp2(St), FMA2(eOWNf0, sp2(So), pre4v0));
      const f32x2 h4v1 = FMA2(eOTHf1, sp2(St), FMA2(eOWNf1, sp2(So), pre4v1));
      // off-path: k3, U_4, partial sum P, next-step pre-closures
      S1 = isQ1 ? St : So;
      S2 = isQ1 ? So : St;
      const float k30 = U0_3 - S1;
      const float k31 =
          __builtin_fmaf(1.5f, S1, __builtin_fmaf(-3.0f, S2, U1_3));
      const float k32 = U2_3 + S2;
      const float U0_4 = __builtin_fmaf(-0.1f, k30, U0);
      const float U1_4 = __builtin_fmaf(-0.1f, k31, U1);
      const float U2_4 = __builtin_fmaf(-0.1f, k32, U2);
      float q0 = k20 + k30;
      const float Q0 = __builtin_fmaf(2.0f, q0, k10) + U0_4;
      const float P0 = __builtin_fmaf(1.0f / 6.0f, Q0, x0);
      float q1 = k21 + k31;
      const float Q1 = __builtin_fmaf(2.0f, q1, k11) + U1_4;
      const float P1 = __builtin_fmaf(1.0f / 6.0f, Q1, x1);
      float q2 = k22 + k32;
      const float Q2 = __builtin_fmaf(2.0f, q2, k12) + U2_4;
      const float P2 = __builtin_fmaf(1.0f / 6.0f, Q2, x2);
      const float C0tn = __builtin_fmaf(unx, 1.0f / 6.0f, C0b);
      const float pU0 = __builtin_fmaf(-0.1f, P0, C0tn);
      const float pU1 = __builtin_fmaf(-0.1f, P1, C1);
      const float pU2 = __builtin_fmaf(-0.1f, P2, C2);
      const float Pa = isQ1 ? P1 : P0;
      const float Pv = isQ1 ? P2 : P0;
      const f32x2 preHv0 = FMA2(wAv0, sp2(Pa), FMA2(wBv0, sp2(Pv), wCv0));
      const f32x2 preHv1 = FMA2(wAv1, sp2(Pa), FMA2(wBv1, sp2(Pv), wCv1));
      // ================= stage 4 =================
      nets(h4v0, h4v1, So, St);
      // close next step's h1 (2 fma from S4-arrival)
      h1v0 = FMA2(eOTH60, sp2(St), FMA2(eOWN60, sp2(So), preHv0));
      h1v1 = FMA2(eOTH61, sp2(St), FMA2(eOWN61, sp2(So), preHv1));
      // off-path (during next step's stage-1 flight): x, U, pre2
      S1 = isQ1 ? St : So;
      S2 = isQ1 ? So : St;
      x0 = __builtin_fmaf(-1.0f / 6.0f, S1, P0);
      x1 = __builtin_fmaf(0.25f, S1, __builtin_fmaf(-0.5f, S2, P1));
      x2 = __builtin_fmaf(1.0f / 6.0f, S2, P2);
      U0 = __builtin_fmaf(1.0f / 60.0f, S1, pU0);
      U1 = __builtin_fmaf(-0.025f, S1, __builtin_fmaf(0.05f, S2, pU1));
      U2 = __builtin_fmaf(-1.0f / 60.0f, S2, pU2);
      const float Ua = isQ1 ? U1 : U0;
      pre2v0 = FMA2(cwAh0, sp2(Ua), FMA2(cwBh0, sp2(U2), h1v0));
      pre2v1 = FMA2(cwAh1, sp2(Ua), FMA2(cwBh1, sp2(U2), h1v1));
    }
    ucur = unext;
  }
}

// ---------------------------------------------------------------------------
// Phase 2: CcNN = eC(z_t) for all (b,t), fully parallel. Verbatim the
// verified round-2/4/5 version.
// ---------------------------------------------------------------------------
__global__ __launch_bounds__(256) void phase2_kernel(
    const float* __restrict__ u, const float* __restrict__ xz0,
    const float* __restrict__ eCW1, const float* __restrict__ eCb1,
    const float* __restrict__ eCW2, const float* __restrict__ eCb2,
    float* __restrict__ out) {
  __shared__ float lw[32][16];
  __shared__ float lw2[32];
  const int tid = threadIdx.x;
  if (tid < 32) {
#pragma unroll
    for (int i = 0; i < 15; ++i) lw[tid][i] = eCW1[i * 32 + tid] * TS;
    lw[tid][15] = eCb1[tid] * TS;
    lw2[tid] = -2.0f * eCW2[tid];
  }
  __syncthreads();

  const int b = blockIdx.x;
  const int t0 = tid << 2;
  const float2* ysrow =
      (const float2*)(out + (size_t)NB * NT * 4) + (size_t)b * NT;
  const float* urow = u + (size_t)b * NT;
  const float* xzr = xz0 + b * 18;

  // window: times t' = t0-5 .. t0+2; t' < 0 comes from z0 (entry t'+5)
  float yw[16], uw[8];
#pragma unroll
  for (int idx = 0; idx < 8; ++idx) {
    const int tp = t0 - 5 + idx;
    float a, c, uu;
    if (tp >= 0) {
      const float2 h = ysrow[tp];
      a = h.x;
      c = h.y;
      uu = urow[tp];
    } else {
      a = xzr[3 + 2 * (tp + 5)];
      c = xzr[4 + 2 * (tp + 5)];
      uu = xzr[13 + (tp + 5)];
    }
    yw[2 * idx] = a;
    yw[2 * idx + 1] = c;
    uw[idx] = uu;
  }

  float acc[4] = {0.f, 0.f, 0.f, 0.f};
  for (int j = 0; j < 32; ++j) {
    const float4 wa = ((const float4*)lw[j])[0];
    const float4 wb = ((const float4*)lw[j])[1];
    const float4 wc = ((const float4*)lw[j])[2];
    const float4 wd = ((const float4*)lw[j])[3];  // .w = scaled bias
    const float w2n = lw2[j];
#pragma unroll
    for (int e = 0; e < 4; ++e) {
      float h = wd.w;
      h = __builtin_fmaf(yw[2 * e + 0], wa.x, h);
      h = __builtin_fmaf(yw[2 * e + 1], wa.y, h);
      h = __builtin_fmaf(yw[2 * e + 2], wa.z, h);
      h = __builtin_fmaf(yw[2 * e + 3], wa.w, h);
      h = __builtin_fmaf(yw[2 * e + 4], wb.x, h);
      h = __builtin_fmaf(yw[2 * e + 5], wb.y, h);
      h = __builtin_fmaf(yw[2 * e + 6], wb.z, h);
      h = __builtin_fmaf(yw[2 * e + 7], wb.w, h);
      h = __builtin_fmaf(yw[2 * e + 8], wc.x, h);
      h = __builtin_fmaf(yw[2 * e + 9], wc.y, h);
      h = __builtin_fmaf(uw[e + 0], wc.z, h);
      h = __builtin_fmaf(uw[e + 1], wc.w, h);
      h = __builtin_fmaf(uw[e + 2], wd.x, h);
      h = __builtin_fmaf(uw[e + 3], wd.y, h);
      h = __builtin_fmaf(uw[e + 4], wd.z, h);
      const float r = RCPF(EXP2F(h) + 1.0f);
      acc[e] = __builtin_fmaf(w2n, r, acc[e]);
    }
  }
  // C = b2 + sum(W2) (uniform addresses -> scalar loads, one-time)
  float sw = 0.0f;
#pragma unroll
  for (int j = 0; j < 32; ++j) sw += eCW2[j];
  const float C = eCb2[0] + sw;
  float* yfrow = out + (size_t)b * NT * 4;
#pragma unroll
  for (int e = 0; e < 4; ++e) {
    yfrow[(t0 + e) * 4 + 3] = acc[e] + C;
  }
}

extern "C" void kernel_launch(void* const* d_in, const int* in_sizes, int n_in,
                              void* d_out, int out_size, void* d_ws,
                              size_t ws_size, hipStream_t stream) {
  const float* u = (const float*)d_in[0];
  const float* xz0 = (const float*)d_in[1];
  const float* r1W1 = (const float*)d_in[2];
  const float* r1b1 = (const float*)d_in[3];
  const float* r1W2 = (const float*)d_in[4];
  const float* r1b2 = (const float*)d_in[5];
  const float* r2W1 = (const float*)d_in[6];
  const float* r2b1 = (const float*)d_in[7];
  const float* r2W2 = (const float*)d_in[8];
  const float* r2b2 = (const float*)d_in[9];
  const float* eCW1 = (const float*)d_in[10];
  const float* eCb1 = (const float*)d_in[11];
  const float* eCW2 = (const float*)d_in[12];
  const float* eCb2 = (const float*)d_in[13];
  float* out = (float*)d_out;

  hipLaunchKernelGGL(phase1_kernel, dim3(NB / 8), dim3(64), 0, stream, u, xz0,
                     r1W1, r1b1, r1W2, r1b2, r2W1, r2b1, r2W2, r2b2, eCW1,
                     eCb1, eCW2, eCb2, out);
  hipLaunchKernelGGL(phase2_kernel, dim3(NB), dim3(256), 0, stream, u, xz0,
                     eCW1, eCb1, eCW2, eCb2, out);
}